// Round 8
// baseline (3184.895 us; speedup 1.0000x reference)
//
#include <hip/hip_runtime.h>

#define HID 256
#define AS_LD 72    // u16; K-loop A-tile row stride (144 B)
#define TB_LD 264   // u16; epilogue transpose row stride (528 B, 16B-aligned)

typedef unsigned short u16;
typedef unsigned int u32;
typedef short bf16x8 __attribute__((ext_vector_type(8)));
typedef float f32x4 __attribute__((ext_vector_type(4)));
typedef u16 u16x8 __attribute__((ext_vector_type(8)));

static __device__ __forceinline__ float bf2f(u16 b) {
    u32 u = ((u32)b) << 16;
    return __uint_as_float(u);
}
static __device__ __forceinline__ u16 f2bf(float f) {
    u32 u = __float_as_uint(f);
    return (u16)((u + 0x7FFFu + ((u >> 16) & 1u)) >> 16);  // RN-even
}

// ---------------------------------------------------------------------------
// Fused gather + GEMM + relu, tile 64 rows x 256 cols, BK=64 (128B granules).
//   A rows from up to three k-concatenated sources:
//     c1 chunks: sum of 6 rows of Sg via graph (bf16, ld 256)
//     c2 chunks: direct rows of Bd            (bf16, ld ldbd, nt-loaded)
//     c3 chunks: fp32 rows of Cf (K < Kc)
//   B = WB [256 cols][ldw k] bf16, L2-hot, register-loaded per chunk.
// Epilogue: 2-pass LDS transpose (32x256) -> full-line nontemporal stores.
// ---------------------------------------------------------------------------
__global__ __launch_bounds__(256, 5) void fused_layer(
    const u16* __restrict__ Sg, const int* __restrict__ graph, int c1,
    const u16* __restrict__ Bd, int ldbd, int c2,
    const float* __restrict__ Cf, int ldcf, int Kc, int c3,
    const u16* __restrict__ WB, int ldw,
    const float* __restrict__ bias,
    u16* __restrict__ C, int M)
{
    __shared__ __align__(16) u16 lds[32 * TB_LD];   // 16,896 B (union: A-tile / transpose)
    u16* As = lds;                                   // 64 x AS_LD view (9,216 B)

    const int t    = threadIdx.x;
    const int w    = t >> 6;
    const int lane = t & 63;
    const int row0 = blockIdx.x * 64;
    const int wc   = w * 64;           // wave's 64 columns
    const int fr   = lane & 15;
    const int fq   = lane >> 4;

    const int g  = t & 7;              // 16B granule within 128B chunk-slice
    const int ra = t >> 3;             // 0..31 -> rows ra, ra+32

    int nbi[2][6];
    const u16* bdp[2] = {nullptr, nullptr};
    if (c1 > 0) {
        #pragma unroll
        for (int s = 0; s < 2; ++s) {
            const int gr = row0 + ra + 32 * s;
            const int* gp = graph + (size_t)(gr < M ? gr : 0) * 6;
            #pragma unroll
            for (int j = 0; j < 6; ++j) nbi[s][j] = __builtin_nontemporal_load(&gp[j]);
        }
    }
    if (c2 > 0) {
        #pragma unroll
        for (int s = 0; s < 2; ++s) {
            const int gr = row0 + ra + 32 * s;
            bdp[s] = Bd + (size_t)(gr < M ? gr : 0) * ldbd;
        }
    }

    f32x4 acc[4][4] = {};
    const int nch = c1 + c2 + c3;
    const int nbf = c1 + c2;           // bf16-typed (pipelined) chunks
    u16x8 rg[12];

    // ---- preload chunk 0 ----
    if (0 < c1) {
        #pragma unroll
        for (int s = 0; s < 2; ++s)
            #pragma unroll
            for (int j = 0; j < 6; ++j)
                rg[s * 6 + j] = *(const u16x8*)(Sg + (size_t)nbi[s][j] * 256 + g * 8);
    } else if (0 < nbf) {
        #pragma unroll
        for (int s = 0; s < 2; ++s)
            rg[s] = __builtin_nontemporal_load((const u16x8*)(bdp[s] + g * 8));
    }

    #pragma unroll 1
    for (int kc = 0; kc < nch; ++kc) {
        __syncthreads();   // previous compute done reading As
        // ---- stage current chunk into LDS ----
        if (kc < c1) {
            #pragma unroll
            for (int s = 0; s < 2; ++s) {
                float sa[8] = {};
                #pragma unroll
                for (int j = 0; j < 6; ++j) {
                    const u16x8 v = rg[s * 6 + j];
                    #pragma unroll
                    for (int e = 0; e < 8; ++e) sa[e] += bf2f(v[e]);
                }
                u16x8 o;
                #pragma unroll
                for (int e = 0; e < 8; ++e) o[e] = f2bf(sa[e]);
                *(u16x8*)(As + (ra + 32 * s) * AS_LD + g * 8) = o;
            }
        } else if (kc < nbf) {
            #pragma unroll
            for (int s = 0; s < 2; ++s)
                *(u16x8*)(As + (ra + 32 * s) * AS_LD + g * 8) = rg[s];
        } else {
            // fp32 source, converted (64 rows x 64 elems; 16 floats/thread)
            const int kb = (kc - nbf) * 64;
            const int r2 = t >> 2, q = t & 3;
            const int gr = row0 + r2;
            u16 tmp[16];
            #pragma unroll
            for (int i = 0; i < 16; ++i) {
                const int k = kb + q * 16 + i;
                const float v = (gr < M && k < Kc) ? Cf[(size_t)gr * ldcf + k] : 0.f;
                tmp[i] = f2bf(v);
            }
            uint4* d = (uint4*)(As + r2 * AS_LD + q * 16);
            d[0] = ((const uint4*)tmp)[0];
            d[1] = ((const uint4*)tmp)[1];
        }
        // ---- prefetch next bf16 chunk (overlaps with MFMA below) ----
        const int kn = kc + 1;
        if (kn < c1) {
            #pragma unroll
            for (int s = 0; s < 2; ++s)
                #pragma unroll
                for (int j = 0; j < 6; ++j)
                    rg[s * 6 + j] = *(const u16x8*)(Sg + (size_t)nbi[s][j] * 256 + kn * 64 + g * 8);
        } else if (kn < nbf) {
            const int k0 = (kn - c1) * 64 + g * 8;
            #pragma unroll
            for (int s = 0; s < 2; ++s)
                rg[s] = __builtin_nontemporal_load((const u16x8*)(bdp[s] + k0));
        }
        __syncthreads();   // As visible

        // ---- B fragments for this chunk (L2-hot), then MFMA ----
        bf16x8 bfv[2][4];
        #pragma unroll
        for (int s = 0; s < 2; ++s)
            #pragma unroll
            for (int j = 0; j < 4; ++j) {
                const int col = wc + j * 16 + fr;
                bfv[s][j] = *(const bf16x8*)(WB + (size_t)col * ldw + kc * 64 + s * 32 + fq * 8);
            }
        #pragma unroll
        for (int s = 0; s < 2; ++s) {
            bf16x8 af[4];
            #pragma unroll
            for (int i = 0; i < 4; ++i)
                af[i] = *(const bf16x8*)(As + (i * 16 + fr) * AS_LD + s * 32 + fq * 8);
            #pragma unroll
            for (int j = 0; j < 4; ++j)
                #pragma unroll
                for (int i = 0; i < 4; ++i)
                    acc[i][j] = __builtin_amdgcn_mfma_f32_16x16x32_bf16(bfv[s][j], af[i], acc[i][j], 0, 0, 0);
        }
    }

    // ---- epilogue: 2-pass transpose through LDS, full-line nt stores ----
    u16* Tb = lds;                          // 32 x TB_LD view
    #pragma unroll
    for (int s2 = 0; s2 < 2; ++s2) {
        __syncthreads();                    // K-loop / previous pass done with lds
        #pragma unroll
        for (int j = 0; j < 4; ++j) {
            const int gc = wc + j * 16 + fq * 4;
            float4 bv = make_float4(0.f, 0.f, 0.f, 0.f);
            if (bias) bv = *(const float4*)&bias[gc];
            #pragma unroll
            for (int ii = 0; ii < 2; ++ii) {
                const int i = s2 * 2 + ii;  // acc row-block
                u16 o[4];
                o[0] = f2bf(fmaxf(acc[i][j][0] + bv.x, 0.f));
                o[1] = f2bf(fmaxf(acc[i][j][1] + bv.y, 0.f));
                o[2] = f2bf(fmaxf(acc[i][j][2] + bv.z, 0.f));
                o[3] = f2bf(fmaxf(acc[i][j][3] + bv.w, 0.f));
                *(uint2*)(Tb + (ii * 16 + fr) * TB_LD + gc) = *(const uint2*)o;
            }
        }
        __syncthreads();                    // half-tile complete
        const int gsl = t & 31;             // 16B granule within 512B row
        const int rb  = t >> 5;             // 0..7
        #pragma unroll
        for (int it2 = 0; it2 < 4; ++it2) {
            const int rl = it2 * 8 + rb;
            const int gr = row0 + s2 * 32 + rl;
            if (gr < M) {
                const u16x8 v = *(const u16x8*)(Tb + rl * TB_LD + gsl * 8);
                __builtin_nontemporal_store(v, (u16x8*)(C + (size_t)gr * 256 + gsl * 8));
            }
        }
    }
}

// WB[n][k] bf16: k<k1 -> src1[n][off1+k]; k1<=k<k1+k2 -> src2[n][off2+k-k1]; else 0
__global__ void build_wb(const float* __restrict__ src1, int lds1, int off1, int k1,
                         const float* __restrict__ src2, int lds2, int off2, int k2,
                         u16* __restrict__ dst, int ldd)
{
    const int n = blockIdx.x;  // 0..255
    for (int k = threadIdx.x; k < ldd; k += blockDim.x) {
        float v = 0.f;
        if (k < k1)           v = src1[(size_t)n * lds1 + off1 + k];
        else if (k < k1 + k2) v = src2[(size_t)n * lds2 + off2 + (k - k1)];
        dst[(size_t)n * ldd + k] = f2bf(v);
    }
}

// FB[e][0:64] = bf16(fbonds[e][0:50]) padded with zeros
__global__ void build_fb(const float* __restrict__ fb, u16* __restrict__ FB, int E)
{
    const int e = blockIdx.x * 4 + (threadIdx.x >> 6);
    if (e >= E) return;
    const int k = threadIdx.x & 63;
    FB[(size_t)e * 64 + k] = (k < 50) ? f2bf(fb[(size_t)e * 50 + k]) : (u16)0;
}

// per-molecule mean over sorted mol_ids; atomh bf16, out fp32
__global__ void segment_mean(const u16* __restrict__ atomh, const int* __restrict__ mol_ids,
                             float* __restrict__ out, int N)
{
    const int m = blockIdx.x;
    const int t = threadIdx.x;
    __shared__ int s_lo, s_hi;
    if (t == 0) {
        int lo = 0, hi = N;
        while (lo < hi) { int mid = (lo + hi) >> 1; if (mol_ids[mid] < m) lo = mid + 1; else hi = mid; }
        s_lo = lo;
        lo = s_lo; hi = N;
        while (lo < hi) { int mid = (lo + hi) >> 1; if (mol_ids[mid] < m + 1) lo = mid + 1; else hi = mid; }
        s_hi = lo;
    }
    __syncthreads();
    const int lo = s_lo, hi = s_hi;
    float sum = 0.f;
    for (int a = lo; a < hi; ++a) sum += bf2f(atomh[(size_t)a * HID + t]);
    const float cnt = (float)((hi - lo) > 1 ? (hi - lo) : 1);
    out[(size_t)m * HID + t] = sum / cnt;
}

extern "C" void kernel_launch(void* const* d_in, const int* in_sizes, int n_in,
                              void* d_out, int out_size, void* d_ws, size_t ws_size,
                              hipStream_t stream)
{
    const float* fatoms = (const float*)d_in[0];
    const float* fbonds = (const float*)d_in[1];
    const int*   agraph = (const int*)d_in[2];
    const int*   bgraph = (const int*)d_in[3];
    const int*   mol_ids = (const int*)d_in[4];
    const float* W_i = (const float*)d_in[7];
    const float* W_h = (const float*)d_in[8];
    const float* W_o = (const float*)d_in[9];
    const float* b_o = (const float*)d_in[10];

    const int N = in_sizes[0] / 39;       // 100000
    const int E = in_sizes[1] / 50;       // 200001
    const int N_MOLS = 1000;
    const int DEPTH = 6;

    const size_t EH = (size_t)E * HID;
    const size_t wbh_sz = (size_t)256 * 320;
    const size_t wbi_sz = (size_t)256 * 64;
    const size_t wbo_sz = (size_t)256 * 320;
    const size_t wsz = wbh_sz + wbi_sz + wbo_sz;
    const size_t fb_sz = (size_t)E * 64;

    const size_t need_nofb = (2 * EH + wsz) * sizeof(u16);
    const size_t need_fb   = (2 * EH + fb_sz + wsz) * sizeof(u16);
    if (ws_size < need_nofb) return;
    const bool use_fb = (ws_size >= need_fb);

    u16* buf0 = (u16*)d_ws;                       // [E][256]
    u16* buf1 = buf0 + EH;                        // [E][256]
    u16* FB   = use_fb ? (buf1 + EH) : nullptr;   // [E][64] bf16 fbonds
    u16* wbh  = (use_fb ? FB + fb_sz : buf1 + EH);
    u16* wbi  = wbh + wbh_sz;
    u16* wbo  = wbi + wbi_sz;

    float* out = (float*)d_out;

    build_wb<<<dim3(256), dim3(64), 0, stream>>>(W_h, 256, 0, 256, W_i, 50, 0, 50, wbh, 320);
    build_wb<<<dim3(256), dim3(64), 0, stream>>>(W_i, 50, 0, 50, W_i, 50, 0, 0, wbi, 64);
    build_wb<<<dim3(256), dim3(64), 0, stream>>>(W_o, 295, 39, 256, W_o, 295, 0, 39, wbo, 320);
    if (use_fb)
        build_fb<<<dim3((E + 3) / 4), dim3(256), 0, stream>>>(fbonds, FB, E);

    const int gE = (E + 63) / 64;     // 3126
    const int gN = (N + 63) / 64;     // 1563

    // layer 0: buf0 = relu(fbonds @ W_i.T)
    if (use_fb)
        fused_layer<<<dim3(gE), dim3(256), 0, stream>>>(
            nullptr, nullptr, 0, FB, 64, 1, nullptr, 0, 0, 0, wbi, 64, nullptr, buf0, E);
    else
        fused_layer<<<dim3(gE), dim3(256), 0, stream>>>(
            nullptr, nullptr, 0, nullptr, 0, 0, fbonds, 50, 50, 1, wbi, 64, nullptr, buf0, E);

    // hidden layers (ping-pong): dst = relu(gather(src)@W_h.T + fbonds@W_i.T)
    u16* src = buf0;
    u16* dst = buf1;
    for (int it = 0; it < DEPTH - 1; ++it) {
        if (use_fb)
            fused_layer<<<dim3(gE), dim3(256), 0, stream>>>(
                src, bgraph, 4, FB, 64, 1, nullptr, 0, 0, 0, wbh, 320, nullptr, dst, E);
        else
            fused_layer<<<dim3(gE), dim3(256), 0, stream>>>(
                src, bgraph, 4, nullptr, 0, 0, fbonds, 50, 50, 1, wbh, 320, nullptr, dst, E);
        u16* tmp = src; src = dst; dst = tmp;
    }
    // after 5 layers: src = buf1 (final message), dst = buf0 (free)

    // output layer: dst = relu(gather_a(src)@W_o[:,39:].T + fatoms@W_o[:,:39].T + b_o)
    fused_layer<<<dim3(gN), dim3(256), 0, stream>>>(
        src, agraph, 4, nullptr, 0, 0, fatoms, 39, 39, 1, wbo, 320, b_o, dst, N);

    // per-molecule mean
    segment_mean<<<dim3(N_MOLS), dim3(256), 0, stream>>>(dst, mol_ids, out, N);
}

// Round 9
// 2291.124 us; speedup vs baseline: 1.3901x; 1.3901x over previous
//
#include <hip/hip_runtime.h>

#define HID 256
#define AS_LD 72    // u16; K-loop A-tile row stride (144 B)
#define TB_LD 264   // u16; epilogue transpose row stride (528 B, 16B-aligned)

typedef unsigned short u16;
typedef unsigned int u32;
typedef short bf16x8 __attribute__((ext_vector_type(8)));
typedef float f32x4 __attribute__((ext_vector_type(4)));
typedef u16 u16x8 __attribute__((ext_vector_type(8)));

static __device__ __forceinline__ float bf2f(u16 b) {
    u32 u = ((u32)b) << 16;
    return __uint_as_float(u);
}
static __device__ __forceinline__ u16 f2bf(float f) {
    u32 u = __float_as_uint(f);
    return (u16)((u + 0x7FFFu + ((u >> 16) & 1u)) >> 16);  // RN-even
}

// ---------------------------------------------------------------------------
// Fused gather + GEMM + relu, tile 64 rows x 256 cols, BK=64 (128B granules).
//   A rows from up to three k-concatenated sources:
//     c1 chunks: sum of 6 rows of Sg via graph (bf16, ld 256)
//     c2 chunks: direct rows of Bd            (bf16, ld ldbd, nt-loaded)
//     c3 chunks: fp32 rows of Cf (K < Kc)
//   B = WB [256 cols][ldw k] bf16, L2-hot, register-loaded per chunk.
// Epilogue: 2-pass LDS transpose (32x256) -> full-line nontemporal stores.
// NOTE: launch_bounds min-waves=4 (VGPR cap 128). 5 forced a 48-VGPR alloc
// -> scratch spills -> 1.7 GB/layer HBM spill traffic (round 8 regression).
// ---------------------------------------------------------------------------
__global__ __launch_bounds__(256, 4) void fused_layer(
    const u16* __restrict__ Sg, const int* __restrict__ graph, int c1,
    const u16* __restrict__ Bd, int ldbd, int c2,
    const float* __restrict__ Cf, int ldcf, int Kc, int c3,
    const u16* __restrict__ WB, int ldw,
    const float* __restrict__ bias,
    u16* __restrict__ C, int M)
{
    __shared__ __align__(16) u16 lds[32 * TB_LD];   // 16,896 B (union: A-tile / transpose)
    u16* As = lds;                                   // 64 x AS_LD view (9,216 B)

    const int t    = threadIdx.x;
    const int w    = t >> 6;
    const int lane = t & 63;
    const int row0 = blockIdx.x * 64;
    const int wc   = w * 64;           // wave's 64 columns
    const int fr   = lane & 15;
    const int fq   = lane >> 4;

    const int g  = t & 7;              // 16B granule within 128B chunk-slice
    const int ra = t >> 3;             // 0..31 -> rows ra, ra+32

    int nbi[2][6];
    const u16* bdp[2] = {nullptr, nullptr};
    if (c1 > 0) {
        #pragma unroll
        for (int s = 0; s < 2; ++s) {
            const int gr = row0 + ra + 32 * s;
            const int* gp = graph + (size_t)(gr < M ? gr : 0) * 6;
            #pragma unroll
            for (int j = 0; j < 6; ++j) nbi[s][j] = __builtin_nontemporal_load(&gp[j]);
        }
    }
    if (c2 > 0) {
        #pragma unroll
        for (int s = 0; s < 2; ++s) {
            const int gr = row0 + ra + 32 * s;
            bdp[s] = Bd + (size_t)(gr < M ? gr : 0) * ldbd;
        }
    }

    f32x4 acc[4][4] = {};
    const int nch = c1 + c2 + c3;
    const int nbf = c1 + c2;           // bf16-typed (pipelined) chunks
    u16x8 rg[12];

    // ---- preload chunk 0 ----
    if (0 < c1) {
        #pragma unroll
        for (int s = 0; s < 2; ++s)
            #pragma unroll
            for (int j = 0; j < 6; ++j)
                rg[s * 6 + j] = *(const u16x8*)(Sg + (size_t)nbi[s][j] * 256 + g * 8);
    } else if (0 < nbf) {
        #pragma unroll
        for (int s = 0; s < 2; ++s)
            rg[s] = __builtin_nontemporal_load((const u16x8*)(bdp[s] + g * 8));
    }

    #pragma unroll 1
    for (int kc = 0; kc < nch; ++kc) {
        __syncthreads();   // previous compute done reading As
        // ---- stage current chunk into LDS ----
        if (kc < c1) {
            #pragma unroll
            for (int s = 0; s < 2; ++s) {
                float sa[8] = {};
                #pragma unroll
                for (int j = 0; j < 6; ++j) {
                    const u16x8 v = rg[s * 6 + j];
                    #pragma unroll
                    for (int e = 0; e < 8; ++e) sa[e] += bf2f(v[e]);
                }
                u16x8 o;
                #pragma unroll
                for (int e = 0; e < 8; ++e) o[e] = f2bf(sa[e]);
                *(u16x8*)(As + (ra + 32 * s) * AS_LD + g * 8) = o;
            }
        } else if (kc < nbf) {
            #pragma unroll
            for (int s = 0; s < 2; ++s)
                *(u16x8*)(As + (ra + 32 * s) * AS_LD + g * 8) = rg[s];
        } else {
            // fp32 source, converted (64 rows x 64 elems; 16 floats/thread)
            const int kb = (kc - nbf) * 64;
            const int r2 = t >> 2, q = t & 3;
            const int gr = row0 + r2;
            u16 tmp[16];
            #pragma unroll
            for (int i = 0; i < 16; ++i) {
                const int k = kb + q * 16 + i;
                const float v = (gr < M && k < Kc) ? Cf[(size_t)gr * ldcf + k] : 0.f;
                tmp[i] = f2bf(v);
            }
            uint4* d = (uint4*)(As + r2 * AS_LD + q * 16);
            d[0] = ((const uint4*)tmp)[0];
            d[1] = ((const uint4*)tmp)[1];
        }
        // ---- prefetch next bf16 chunk (overlaps with MFMA below) ----
        const int kn = kc + 1;
        if (kn < c1) {
            #pragma unroll
            for (int s = 0; s < 2; ++s)
                #pragma unroll
                for (int j = 0; j < 6; ++j)
                    rg[s * 6 + j] = *(const u16x8*)(Sg + (size_t)nbi[s][j] * 256 + kn * 64 + g * 8);
        } else if (kn < nbf) {
            const int k0 = (kn - c1) * 64 + g * 8;
            #pragma unroll
            for (int s = 0; s < 2; ++s)
                rg[s] = __builtin_nontemporal_load((const u16x8*)(bdp[s] + k0));
        }
        __syncthreads();   // As visible

        // ---- B fragments for this chunk (L2-hot), then MFMA ----
        bf16x8 bfv[2][4];
        #pragma unroll
        for (int s = 0; s < 2; ++s)
            #pragma unroll
            for (int j = 0; j < 4; ++j) {
                const int col = wc + j * 16 + fr;
                bfv[s][j] = *(const bf16x8*)(WB + (size_t)col * ldw + kc * 64 + s * 32 + fq * 8);
            }
        #pragma unroll
        for (int s = 0; s < 2; ++s) {
            bf16x8 af[4];
            #pragma unroll
            for (int i = 0; i < 4; ++i)
                af[i] = *(const bf16x8*)(As + (i * 16 + fr) * AS_LD + s * 32 + fq * 8);
            #pragma unroll
            for (int j = 0; j < 4; ++j)
                #pragma unroll
                for (int i = 0; i < 4; ++i)
                    acc[i][j] = __builtin_amdgcn_mfma_f32_16x16x32_bf16(bfv[s][j], af[i], acc[i][j], 0, 0, 0);
        }
    }

    // ---- epilogue: 2-pass transpose through LDS, full-line nt stores ----
    u16* Tb = lds;                          // 32 x TB_LD view
    #pragma unroll
    for (int s2 = 0; s2 < 2; ++s2) {
        __syncthreads();                    // K-loop / previous pass done with lds
        #pragma unroll
        for (int j = 0; j < 4; ++j) {
            const int gc = wc + j * 16 + fq * 4;
            float4 bv = make_float4(0.f, 0.f, 0.f, 0.f);
            if (bias) bv = *(const float4*)&bias[gc];
            #pragma unroll
            for (int ii = 0; ii < 2; ++ii) {
                const int i = s2 * 2 + ii;  // acc row-block
                u16 o[4];
                o[0] = f2bf(fmaxf(acc[i][j][0] + bv.x, 0.f));
                o[1] = f2bf(fmaxf(acc[i][j][1] + bv.y, 0.f));
                o[2] = f2bf(fmaxf(acc[i][j][2] + bv.z, 0.f));
                o[3] = f2bf(fmaxf(acc[i][j][3] + bv.w, 0.f));
                *(uint2*)(Tb + (ii * 16 + fr) * TB_LD + gc) = *(const uint2*)o;
            }
        }
        __syncthreads();                    // half-tile complete
        const int gsl = t & 31;             // 16B granule within 512B row
        const int rb  = t >> 5;             // 0..7
        #pragma unroll
        for (int it2 = 0; it2 < 4; ++it2) {
            const int rl = it2 * 8 + rb;
            const int gr = row0 + s2 * 32 + rl;
            if (gr < M) {
                const u16x8 v = *(const u16x8*)(Tb + rl * TB_LD + gsl * 8);
                __builtin_nontemporal_store(v, (u16x8*)(C + (size_t)gr * 256 + gsl * 8));
            }
        }
    }
}

// WB[n][k] bf16: k<k1 -> src1[n][off1+k]; k1<=k<k1+k2 -> src2[n][off2+k-k1]; else 0
__global__ void build_wb(const float* __restrict__ src1, int lds1, int off1, int k1,
                         const float* __restrict__ src2, int lds2, int off2, int k2,
                         u16* __restrict__ dst, int ldd)
{
    const int n = blockIdx.x;  // 0..255
    for (int k = threadIdx.x; k < ldd; k += blockDim.x) {
        float v = 0.f;
        if (k < k1)           v = src1[(size_t)n * lds1 + off1 + k];
        else if (k < k1 + k2) v = src2[(size_t)n * lds2 + off2 + (k - k1)];
        dst[(size_t)n * ldd + k] = f2bf(v);
    }
}

// FB[e][0:64] = bf16(fbonds[e][0:50]) padded with zeros
__global__ void build_fb(const float* __restrict__ fb, u16* __restrict__ FB, int E)
{
    const int e = blockIdx.x * 4 + (threadIdx.x >> 6);
    if (e >= E) return;
    const int k = threadIdx.x & 63;
    FB[(size_t)e * 64 + k] = (k < 50) ? f2bf(fb[(size_t)e * 50 + k]) : (u16)0;
}

// per-molecule mean over sorted mol_ids; atomh bf16, out fp32
__global__ void segment_mean(const u16* __restrict__ atomh, const int* __restrict__ mol_ids,
                             float* __restrict__ out, int N)
{
    const int m = blockIdx.x;
    const int t = threadIdx.x;
    __shared__ int s_lo, s_hi;
    if (t == 0) {
        int lo = 0, hi = N;
        while (lo < hi) { int mid = (lo + hi) >> 1; if (mol_ids[mid] < m) lo = mid + 1; else hi = mid; }
        s_lo = lo;
        lo = s_lo; hi = N;
        while (lo < hi) { int mid = (lo + hi) >> 1; if (mol_ids[mid] < m + 1) lo = mid + 1; else hi = mid; }
        s_hi = lo;
    }
    __syncthreads();
    const int lo = s_lo, hi = s_hi;
    float sum = 0.f;
    for (int a = lo; a < hi; ++a) sum += bf2f(atomh[(size_t)a * HID + t]);
    const float cnt = (float)((hi - lo) > 1 ? (hi - lo) : 1);
    out[(size_t)m * HID + t] = sum / cnt;
}

extern "C" void kernel_launch(void* const* d_in, const int* in_sizes, int n_in,
                              void* d_out, int out_size, void* d_ws, size_t ws_size,
                              hipStream_t stream)
{
    const float* fatoms = (const float*)d_in[0];
    const float* fbonds = (const float*)d_in[1];
    const int*   agraph = (const int*)d_in[2];
    const int*   bgraph = (const int*)d_in[3];
    const int*   mol_ids = (const int*)d_in[4];
    const float* W_i = (const float*)d_in[7];
    const float* W_h = (const float*)d_in[8];
    const float* W_o = (const float*)d_in[9];
    const float* b_o = (const float*)d_in[10];

    const int N = in_sizes[0] / 39;       // 100000
    const int E = in_sizes[1] / 50;       // 200001
    const int N_MOLS = 1000;
    const int DEPTH = 6;

    const size_t EH = (size_t)E * HID;
    const size_t wbh_sz = (size_t)256 * 320;
    const size_t wbi_sz = (size_t)256 * 64;
    const size_t wbo_sz = (size_t)256 * 320;
    const size_t wsz = wbh_sz + wbi_sz + wbo_sz;
    const size_t fb_sz = (size_t)E * 64;

    const size_t need_nofb = (2 * EH + wsz) * sizeof(u16);
    const size_t need_fb   = (2 * EH + fb_sz + wsz) * sizeof(u16);
    if (ws_size < need_nofb) return;
    const bool use_fb = (ws_size >= need_fb);

    u16* buf0 = (u16*)d_ws;                       // [E][256]
    u16* buf1 = buf0 + EH;                        // [E][256]
    u16* FB   = use_fb ? (buf1 + EH) : nullptr;   // [E][64] bf16 fbonds
    u16* wbh  = (use_fb ? FB + fb_sz : buf1 + EH);
    u16* wbi  = wbh + wbh_sz;
    u16* wbo  = wbi + wbi_sz;

    float* out = (float*)d_out;

    build_wb<<<dim3(256), dim3(64), 0, stream>>>(W_h, 256, 0, 256, W_i, 50, 0, 50, wbh, 320);
    build_wb<<<dim3(256), dim3(64), 0, stream>>>(W_i, 50, 0, 50, W_i, 50, 0, 0, wbi, 64);
    build_wb<<<dim3(256), dim3(64), 0, stream>>>(W_o, 295, 39, 256, W_o, 295, 0, 39, wbo, 320);
    if (use_fb)
        build_fb<<<dim3((E + 3) / 4), dim3(256), 0, stream>>>(fbonds, FB, E);

    const int gE = (E + 63) / 64;     // 3126
    const int gN = (N + 63) / 64;     // 1563

    // layer 0: buf0 = relu(fbonds @ W_i.T)
    if (use_fb)
        fused_layer<<<dim3(gE), dim3(256), 0, stream>>>(
            nullptr, nullptr, 0, FB, 64, 1, nullptr, 0, 0, 0, wbi, 64, nullptr, buf0, E);
    else
        fused_layer<<<dim3(gE), dim3(256), 0, stream>>>(
            nullptr, nullptr, 0, nullptr, 0, 0, fbonds, 50, 50, 1, wbi, 64, nullptr, buf0, E);

    // hidden layers (ping-pong): dst = relu(gather(src)@W_h.T + fbonds@W_i.T)
    u16* src = buf0;
    u16* dst = buf1;
    for (int it = 0; it < DEPTH - 1; ++it) {
        if (use_fb)
            fused_layer<<<dim3(gE), dim3(256), 0, stream>>>(
                src, bgraph, 4, FB, 64, 1, nullptr, 0, 0, 0, wbh, 320, nullptr, dst, E);
        else
            fused_layer<<<dim3(gE), dim3(256), 0, stream>>>(
                src, bgraph, 4, nullptr, 0, 0, fbonds, 50, 50, 1, wbh, 320, nullptr, dst, E);
        u16* tmp = src; src = dst; dst = tmp;
    }
    // after 5 layers: src = buf1 (final message), dst = buf0 (free)

    // output layer: dst = relu(gather_a(src)@W_o[:,39:].T + fatoms@W_o[:,:39].T + b_o)
    fused_layer<<<dim3(gN), dim3(256), 0, stream>>>(
        src, agraph, 4, nullptr, 0, 0, fatoms, 39, 39, 1, wbo, 320, b_o, dst, N);

    // per-molecule mean
    segment_mean<<<dim3(N_MOLS), dim3(256), 0, stream>>>(dst, mol_ids, out, N);
}

// Round 10
// 1770.012 us; speedup vs baseline: 1.7994x; 1.2944x over previous
//
#include <hip/hip_runtime.h>

#define HID 256
#define AS_LD 72    // u16; K-loop A-tile row stride (144 B)
#define TB_LD 264   // u16; epilogue transpose row stride (528 B, 16B-aligned)

typedef unsigned short u16;
typedef unsigned int u32;
typedef short bf16x8 __attribute__((ext_vector_type(8)));
typedef float f32x4 __attribute__((ext_vector_type(4)));
typedef u16 u16x8 __attribute__((ext_vector_type(8)));

static __device__ __forceinline__ float bf2f(u16 b) {
    u32 u = ((u32)b) << 16;
    return __uint_as_float(u);
}
static __device__ __forceinline__ u16 f2bf(float f) {
    u32 u = __float_as_uint(f);
    return (u16)((u + 0x7FFFu + ((u >> 16) & 1u)) >> 16);  // RN-even
}

// ---------------------------------------------------------------------------
// Fused gather + GEMM + relu, tile 64 rows x 256 cols, BK=64 (128B granules).
//   A rows from up to three k-concatenated sources:
//     c1 chunks: sum of 6 rows of Sg via graph (bf16, ld 256, cached loads)
//     c2 chunks: direct rows of Bd            (bf16, ld ldbd, nt-loaded)
//     c3 chunks: fp32 rows of Cf (K < Kc)
//   B = WB [256 cols][ldw k] bf16, L2-hot, phase-local register loads.
// All gather/B loads are JIT (phase-local liveness) so VGPR+AGPR fits the
// 128/wave unified budget at 4 waves/SIMD: AGPR 64 (acc) + ~60 VGPR.
// r8/r9 lesson: launch_bounds waves=5/4 with cross-phase prefetch regs
// spilled to scratch (0.8-1.7 GB/layer HBM spill traffic).
// Epilogue: 2-pass LDS transpose (32x256) -> full-line nontemporal stores.
// ---------------------------------------------------------------------------
__global__ __launch_bounds__(256, 4) void fused_layer(
    const u16* __restrict__ Sg, const int* __restrict__ graph, int c1,
    const u16* __restrict__ Bd, int ldbd, int c2,
    const float* __restrict__ Cf, int ldcf, int Kc, int c3,
    const u16* __restrict__ WB, int ldw,
    const float* __restrict__ bias,
    u16* __restrict__ C, int M)
{
    __shared__ __align__(16) u16 lds[32 * TB_LD];   // 16,896 B (union: A-tile / transpose)
    u16* As = lds;                                   // 64 x AS_LD view (9,216 B)

    const int t    = threadIdx.x;
    const int w    = t >> 6;
    const int lane = t & 63;
    const int row0 = blockIdx.x * 64;
    const int wc   = w * 64;           // wave's 64 columns
    const int fr   = lane & 15;
    const int fq   = lane >> 4;

    const int g  = t & 7;              // 16B granule within 128B chunk-slice
    const int ra = t >> 3;             // 0..31 -> rows ra, ra+32

    int nbi[2][6];
    const u16* bdp[2] = {nullptr, nullptr};
    if (c1 > 0) {
        #pragma unroll
        for (int s = 0; s < 2; ++s) {
            const int gr = row0 + ra + 32 * s;
            const int* gp = graph + (size_t)(gr < M ? gr : 0) * 6;
            #pragma unroll
            for (int j = 0; j < 6; ++j) nbi[s][j] = __builtin_nontemporal_load(&gp[j]);
        }
    }
    if (c2 > 0) {
        #pragma unroll
        for (int s = 0; s < 2; ++s) {
            const int gr = row0 + ra + 32 * s;
            bdp[s] = Bd + (size_t)(gr < M ? gr : 0) * ldbd;
        }
    }

    f32x4 acc[4][4] = {};
    const int nch = c1 + c2 + c3;
    const int nbf = c1 + c2;           // bf16-typed chunks

    #pragma unroll 1
    for (int kc = 0; kc < nch; ++kc) {
        __syncthreads();   // previous compute done reading As
        // ---- stage current chunk into LDS (JIT loads, phase-local regs) ----
        if (kc < c1) {
            u16x8 v[2][6];
            #pragma unroll
            for (int s = 0; s < 2; ++s)
                #pragma unroll
                for (int j = 0; j < 6; ++j)
                    v[s][j] = *(const u16x8*)(Sg + (size_t)nbi[s][j] * 256 + kc * 64 + g * 8);
            #pragma unroll
            for (int s = 0; s < 2; ++s) {
                float sa[8] = {};
                #pragma unroll
                for (int j = 0; j < 6; ++j)
                    #pragma unroll
                    for (int e = 0; e < 8; ++e) sa[e] += bf2f(v[s][j][e]);
                u16x8 o;
                #pragma unroll
                for (int e = 0; e < 8; ++e) o[e] = f2bf(sa[e]);
                *(u16x8*)(As + (ra + 32 * s) * AS_LD + g * 8) = o;
            }
        } else if (kc < nbf) {
            const int k0 = (kc - c1) * 64 + g * 8;
            u16x8 v[2];
            #pragma unroll
            for (int s = 0; s < 2; ++s)
                v[s] = __builtin_nontemporal_load((const u16x8*)(bdp[s] + k0));
            #pragma unroll
            for (int s = 0; s < 2; ++s)
                *(u16x8*)(As + (ra + 32 * s) * AS_LD + g * 8) = v[s];
        } else {
            // fp32 source, converted (64 rows x 64 elems; 16 floats/thread)
            const int kb = (kc - nbf) * 64;
            const int r2 = t >> 2, q = t & 3;
            const int gr = row0 + r2;
            u16 tmp[16];
            #pragma unroll
            for (int i = 0; i < 16; ++i) {
                const int k = kb + q * 16 + i;
                const float v = (gr < M && k < Kc) ? Cf[(size_t)gr * ldcf + k] : 0.f;
                tmp[i] = f2bf(v);
            }
            uint4* d = (uint4*)(As + r2 * AS_LD + q * 16);
            d[0] = ((const uint4*)tmp)[0];
            d[1] = ((const uint4*)tmp)[1];
        }
        __syncthreads();   // As visible

        // ---- compute: per s-step, JIT B frags (L2-hot) then 16 MFMAs ----
        #pragma unroll
        for (int s = 0; s < 2; ++s) {
            bf16x8 bq[4];
            #pragma unroll
            for (int j = 0; j < 4; ++j) {
                const int col = wc + j * 16 + fr;
                bq[j] = *(const bf16x8*)(WB + (size_t)col * ldw + kc * 64 + s * 32 + fq * 8);
            }
            bf16x8 af[4];
            #pragma unroll
            for (int i = 0; i < 4; ++i)
                af[i] = *(const bf16x8*)(As + (i * 16 + fr) * AS_LD + s * 32 + fq * 8);
            #pragma unroll
            for (int j = 0; j < 4; ++j)
                #pragma unroll
                for (int i = 0; i < 4; ++i)
                    acc[i][j] = __builtin_amdgcn_mfma_f32_16x16x32_bf16(bq[j], af[i], acc[i][j], 0, 0, 0);
        }
    }

    // ---- epilogue: 2-pass transpose through LDS, full-line nt stores ----
    u16* Tb = lds;                          // 32 x TB_LD view
    #pragma unroll
    for (int s2 = 0; s2 < 2; ++s2) {
        __syncthreads();                    // K-loop / previous pass done with lds
        #pragma unroll
        for (int j = 0; j < 4; ++j) {
            const int gc = wc + j * 16 + fq * 4;
            float4 bv = make_float4(0.f, 0.f, 0.f, 0.f);
            if (bias) bv = *(const float4*)&bias[gc];
            #pragma unroll
            for (int ii = 0; ii < 2; ++ii) {
                const int i = s2 * 2 + ii;  // acc row-block
                u16 o[4];
                o[0] = f2bf(fmaxf(acc[i][j][0] + bv.x, 0.f));
                o[1] = f2bf(fmaxf(acc[i][j][1] + bv.y, 0.f));
                o[2] = f2bf(fmaxf(acc[i][j][2] + bv.z, 0.f));
                o[3] = f2bf(fmaxf(acc[i][j][3] + bv.w, 0.f));
                *(uint2*)(Tb + (ii * 16 + fr) * TB_LD + gc) = *(const uint2*)o;
            }
        }
        __syncthreads();                    // half-tile complete
        const int gsl = t & 31;             // 16B granule within 512B row
        const int rb  = t >> 5;             // 0..7
        #pragma unroll
        for (int it2 = 0; it2 < 4; ++it2) {
            const int rl = it2 * 8 + rb;
            const int gr = row0 + s2 * 32 + rl;
            if (gr < M) {
                const u16x8 v = *(const u16x8*)(Tb + rl * TB_LD + gsl * 8);
                __builtin_nontemporal_store(v, (u16x8*)(C + (size_t)gr * 256 + gsl * 8));
            }
        }
    }
}

// WB[n][k] bf16: k<k1 -> src1[n][off1+k]; k1<=k<k1+k2 -> src2[n][off2+k-k1]; else 0
__global__ void build_wb(const float* __restrict__ src1, int lds1, int off1, int k1,
                         const float* __restrict__ src2, int lds2, int off2, int k2,
                         u16* __restrict__ dst, int ldd)
{
    const int n = blockIdx.x;  // 0..255
    for (int k = threadIdx.x; k < ldd; k += blockDim.x) {
        float v = 0.f;
        if (k < k1)           v = src1[(size_t)n * lds1 + off1 + k];
        else if (k < k1 + k2) v = src2[(size_t)n * lds2 + off2 + (k - k1)];
        dst[(size_t)n * ldd + k] = f2bf(v);
    }
}

// FB[e][0:64] = bf16(fbonds[e][0:50]) padded with zeros
__global__ void build_fb(const float* __restrict__ fb, u16* __restrict__ FB, int E)
{
    const int e = blockIdx.x * 4 + (threadIdx.x >> 6);
    if (e >= E) return;
    const int k = threadIdx.x & 63;
    FB[(size_t)e * 64 + k] = (k < 50) ? f2bf(fb[(size_t)e * 50 + k]) : (u16)0;
}

// per-molecule mean over sorted mol_ids; atomh bf16, out fp32
__global__ void segment_mean(const u16* __restrict__ atomh, const int* __restrict__ mol_ids,
                             float* __restrict__ out, int N)
{
    const int m = blockIdx.x;
    const int t = threadIdx.x;
    __shared__ int s_lo, s_hi;
    if (t == 0) {
        int lo = 0, hi = N;
        while (lo < hi) { int mid = (lo + hi) >> 1; if (mol_ids[mid] < m) lo = mid + 1; else hi = mid; }
        s_lo = lo;
        lo = s_lo; hi = N;
        while (lo < hi) { int mid = (lo + hi) >> 1; if (mol_ids[mid] < m + 1) lo = mid + 1; else hi = mid; }
        s_hi = lo;
    }
    __syncthreads();
    const int lo = s_lo, hi = s_hi;
    float sum = 0.f;
    for (int a = lo; a < hi; ++a) sum += bf2f(atomh[(size_t)a * HID + t]);
    const float cnt = (float)((hi - lo) > 1 ? (hi - lo) : 1);
    out[(size_t)m * HID + t] = sum / cnt;
}

extern "C" void kernel_launch(void* const* d_in, const int* in_sizes, int n_in,
                              void* d_out, int out_size, void* d_ws, size_t ws_size,
                              hipStream_t stream)
{
    const float* fatoms = (const float*)d_in[0];
    const float* fbonds = (const float*)d_in[1];
    const int*   agraph = (const int*)d_in[2];
    const int*   bgraph = (const int*)d_in[3];
    const int*   mol_ids = (const int*)d_in[4];
    const float* W_i = (const float*)d_in[7];
    const float* W_h = (const float*)d_in[8];
    const float* W_o = (const float*)d_in[9];
    const float* b_o = (const float*)d_in[10];

    const int N = in_sizes[0] / 39;       // 100000
    const int E = in_sizes[1] / 50;       // 200001
    const int N_MOLS = 1000;
    const int DEPTH = 6;

    const size_t EH = (size_t)E * HID;
    const size_t wbh_sz = (size_t)256 * 320;
    const size_t wbi_sz = (size_t)256 * 64;
    const size_t wbo_sz = (size_t)256 * 320;
    const size_t wsz = wbh_sz + wbi_sz + wbo_sz;
    const size_t fb_sz = (size_t)E * 64;

    const size_t need_nofb = (2 * EH + wsz) * sizeof(u16);
    const size_t need_fb   = (2 * EH + fb_sz + wsz) * sizeof(u16);
    if (ws_size < need_nofb) return;
    const bool use_fb = (ws_size >= need_fb);

    u16* buf0 = (u16*)d_ws;                       // [E][256]
    u16* buf1 = buf0 + EH;                        // [E][256]
    u16* FB   = use_fb ? (buf1 + EH) : nullptr;   // [E][64] bf16 fbonds
    u16* wbh  = (use_fb ? FB + fb_sz : buf1 + EH);
    u16* wbi  = wbh + wbh_sz;
    u16* wbo  = wbi + wbi_sz;

    float* out = (float*)d_out;

    build_wb<<<dim3(256), dim3(64), 0, stream>>>(W_h, 256, 0, 256, W_i, 50, 0, 50, wbh, 320);
    build_wb<<<dim3(256), dim3(64), 0, stream>>>(W_i, 50, 0, 50, W_i, 50, 0, 0, wbi, 64);
    build_wb<<<dim3(256), dim3(64), 0, stream>>>(W_o, 295, 39, 256, W_o, 295, 0, 39, wbo, 320);
    if (use_fb)
        build_fb<<<dim3((E + 3) / 4), dim3(256), 0, stream>>>(fbonds, FB, E);

    const int gE = (E + 63) / 64;     // 3126
    const int gN = (N + 63) / 64;     // 1563

    // layer 0: buf0 = relu(fbonds @ W_i.T)
    if (use_fb)
        fused_layer<<<dim3(gE), dim3(256), 0, stream>>>(
            nullptr, nullptr, 0, FB, 64, 1, nullptr, 0, 0, 0, wbi, 64, nullptr, buf0, E);
    else
        fused_layer<<<dim3(gE), dim3(256), 0, stream>>>(
            nullptr, nullptr, 0, nullptr, 0, 0, fbonds, 50, 50, 1, wbi, 64, nullptr, buf0, E);

    // hidden layers (ping-pong): dst = relu(gather(src)@W_h.T + fbonds@W_i.T)
    u16* src = buf0;
    u16* dst = buf1;
    for (int it = 0; it < DEPTH - 1; ++it) {
        if (use_fb)
            fused_layer<<<dim3(gE), dim3(256), 0, stream>>>(
                src, bgraph, 4, FB, 64, 1, nullptr, 0, 0, 0, wbh, 320, nullptr, dst, E);
        else
            fused_layer<<<dim3(gE), dim3(256), 0, stream>>>(
                src, bgraph, 4, nullptr, 0, 0, fbonds, 50, 50, 1, wbh, 320, nullptr, dst, E);
        u16* tmp = src; src = dst; dst = tmp;
    }
    // after 5 layers: src = buf1 (final message), dst = buf0 (free)

    // output layer: dst = relu(gather_a(src)@W_o[:,39:].T + fatoms@W_o[:,:39].T + b_o)
    fused_layer<<<dim3(gN), dim3(256), 0, stream>>>(
        src, agraph, 4, nullptr, 0, 0, fatoms, 39, 39, 1, wbo, 320, b_o, dst, N);

    // per-molecule mean
    segment_mean<<<dim3(N_MOLS), dim3(256), 0, stream>>>(dst, mol_ids, out, N);
}

// Round 11
// 1029.559 us; speedup vs baseline: 3.0935x; 1.7192x over previous
//
#include <hip/hip_runtime.h>

#define HID 256
#define AS_LD 72    // u16; K-loop A-tile row stride (144 B)
#define TB_LD 264   // u16; epilogue transpose row stride (528 B, 16B-aligned)

typedef unsigned short u16;
typedef unsigned int u32;
typedef short bf16x8 __attribute__((ext_vector_type(8)));
typedef float f32x4 __attribute__((ext_vector_type(4)));
typedef u16 u16x8 __attribute__((ext_vector_type(8)));

static __device__ __forceinline__ float bf2f(u16 b) {
    u32 u = ((u32)b) << 16;
    return __uint_as_float(u);
}
static __device__ __forceinline__ u16 f2bf(float f) {
    u32 u = __float_as_uint(f);
    return (u16)((u + 0x7FFFu + ((u >> 16) & 1u)) >> 16);  // RN-even
}

// ---------------------------------------------------------------------------
// Fused gather + GEMM + relu, tile 64 rows x 256 cols, BK=64, 512 threads.
// 8 waves, each 64 rows x 32 cols -> acc = 32 AGPRs/lane (fits 128-unified
// budget at 4 waves/SIMD with ~70 VGPRs; r8-r10 spilled because 64-AGPR acc
// + staging regs exceeded it).
//   A rows from up to three k-concatenated sources:
//     c1 chunks: sum of 6 rows of Sg via graph (bf16, ld 256, cached loads)
//     c2 chunks: direct rows of Bd            (bf16, ld ldbd, nt-loaded)
//     c3 chunks: fp32 rows of Cf (K < Kc)
//   B = WB [256 cols][ldw k] bf16, L2-hot, phase-local register loads.
// Staging: one row per thread (6 JIT u16x8 loads + fp32 sum -> LDS).
// Epilogue: 2-pass LDS transpose (32x256) -> full-line nontemporal stores.
// ---------------------------------------------------------------------------
__global__ __launch_bounds__(512, 4) void fused_layer(
    const u16* __restrict__ Sg, const int* __restrict__ graph, int c1,
    const u16* __restrict__ Bd, int ldbd, int c2,
    const float* __restrict__ Cf, int ldcf, int Kc, int c3,
    const u16* __restrict__ WB, int ldw,
    const float* __restrict__ bias,
    u16* __restrict__ C, int M)
{
    __shared__ __align__(16) u16 lds[32 * TB_LD];   // 16,896 B (union: A-tile / transpose)
    u16* As = lds;                                   // 64 x AS_LD view (9,216 B)

    const int t    = threadIdx.x;
    const int w    = t >> 6;           // 0..7
    const int lane = t & 63;
    const int row0 = blockIdx.x * 64;
    const int wc   = w * 32;           // wave's 32 columns
    const int fr   = lane & 15;
    const int fq   = lane >> 4;

    const int g  = t & 7;              // 16B granule within 128B row-chunk
    const int ra = t >> 3;             // 0..63 -> one row per thread

    int nbi[6];
    const u16* bdp = nullptr;
    {
        const int gr = row0 + ra;
        if (c1 > 0) {
            const int* gp = graph + (size_t)(gr < M ? gr : 0) * 6;
            #pragma unroll
            for (int j = 0; j < 6; ++j) nbi[j] = __builtin_nontemporal_load(&gp[j]);
        }
        if (c2 > 0) bdp = Bd + (size_t)(gr < M ? gr : 0) * ldbd;
    }

    f32x4 acc[4][2] = {};
    const int nch = c1 + c2 + c3;
    const int nbf = c1 + c2;           // bf16-typed chunks

    #pragma unroll 1
    for (int kc = 0; kc < nch; ++kc) {
        __syncthreads();   // previous compute done reading As
        // ---- stage current chunk into LDS (one row per thread, JIT) ----
        if (kc < c1) {
            u16x8 v[6];
            #pragma unroll
            for (int j = 0; j < 6; ++j)
                v[j] = *(const u16x8*)(Sg + (size_t)nbi[j] * 256 + kc * 64 + g * 8);
            float sa[8] = {};
            #pragma unroll
            for (int j = 0; j < 6; ++j)
                #pragma unroll
                for (int e = 0; e < 8; ++e) sa[e] += bf2f(v[j][e]);
            u16x8 o;
            #pragma unroll
            for (int e = 0; e < 8; ++e) o[e] = f2bf(sa[e]);
            *(u16x8*)(As + ra * AS_LD + g * 8) = o;
        } else if (kc < nbf) {
            const u16x8 v = __builtin_nontemporal_load(
                (const u16x8*)(bdp + (kc - c1) * 64 + g * 8));
            *(u16x8*)(As + ra * AS_LD + g * 8) = v;
        } else {
            // fp32 source, converted: thread handles row ra, cols g*8..g*8+7
            const int kb = (kc - nbf) * 64;
            const int gr = row0 + ra;
            u16 tmp[8];
            #pragma unroll
            for (int i = 0; i < 8; ++i) {
                const int k = kb + g * 8 + i;
                const float v = (gr < M && k < Kc) ? Cf[(size_t)gr * ldcf + k] : 0.f;
                tmp[i] = f2bf(v);
            }
            *(uint4*)(As + ra * AS_LD + g * 8) = *(const uint4*)tmp;
        }
        __syncthreads();   // As visible

        // ---- compute: per s-step, JIT B frags (L2-hot) then 8 MFMAs ----
        #pragma unroll
        for (int s = 0; s < 2; ++s) {
            bf16x8 bq[2];
            #pragma unroll
            for (int j = 0; j < 2; ++j) {
                const int col = wc + j * 16 + fr;
                bq[j] = *(const bf16x8*)(WB + (size_t)col * ldw + kc * 64 + s * 32 + fq * 8);
            }
            bf16x8 af[4];
            #pragma unroll
            for (int i = 0; i < 4; ++i)
                af[i] = *(const bf16x8*)(As + (i * 16 + fr) * AS_LD + s * 32 + fq * 8);
            #pragma unroll
            for (int j = 0; j < 2; ++j)
                #pragma unroll
                for (int i = 0; i < 4; ++i)
                    acc[i][j] = __builtin_amdgcn_mfma_f32_16x16x32_bf16(bq[j], af[i], acc[i][j], 0, 0, 0);
        }
    }

    // ---- epilogue: 2-pass transpose through LDS, full-line nt stores ----
    // acc[i][j]: C-rows i*16+fr, C-cols wc + j*16 + fq*4 .. +3
    u16* Tb = lds;                          // 32 x TB_LD view
    #pragma unroll
    for (int s2 = 0; s2 < 2; ++s2) {
        __syncthreads();                    // K-loop / previous pass done with lds
        #pragma unroll
        for (int j = 0; j < 2; ++j) {
            const int gc = wc + j * 16 + fq * 4;
            float4 bv = make_float4(0.f, 0.f, 0.f, 0.f);
            if (bias) bv = *(const float4*)&bias[gc];
            #pragma unroll
            for (int ii = 0; ii < 2; ++ii) {
                const int i = s2 * 2 + ii;  // acc row-block
                u16 o[4];
                o[0] = f2bf(fmaxf(acc[i][j][0] + bv.x, 0.f));
                o[1] = f2bf(fmaxf(acc[i][j][1] + bv.y, 0.f));
                o[2] = f2bf(fmaxf(acc[i][j][2] + bv.z, 0.f));
                o[3] = f2bf(fmaxf(acc[i][j][3] + bv.w, 0.f));
                *(uint2*)(Tb + (ii * 16 + fr) * TB_LD + gc) = *(const uint2*)o;
            }
        }
        __syncthreads();                    // half-tile complete
        const int gsl = t & 31;             // 16B granule within 512B row
        const int rb  = t >> 5;             // 0..15
        #pragma unroll
        for (int it2 = 0; it2 < 2; ++it2) {
            const int rl = it2 * 16 + rb;
            const int gr = row0 + s2 * 32 + rl;
            if (gr < M) {
                const u16x8 v = *(const u16x8*)(Tb + rl * TB_LD + gsl * 8);
                __builtin_nontemporal_store(v, (u16x8*)(C + (size_t)gr * 256 + gsl * 8));
            }
        }
    }
}

// WB[n][k] bf16: k<k1 -> src1[n][off1+k]; k1<=k<k1+k2 -> src2[n][off2+k-k1]; else 0
__global__ void build_wb(const float* __restrict__ src1, int lds1, int off1, int k1,
                         const float* __restrict__ src2, int lds2, int off2, int k2,
                         u16* __restrict__ dst, int ldd)
{
    const int n = blockIdx.x;  // 0..255
    for (int k = threadIdx.x; k < ldd; k += blockDim.x) {
        float v = 0.f;
        if (k < k1)           v = src1[(size_t)n * lds1 + off1 + k];
        else if (k < k1 + k2) v = src2[(size_t)n * lds2 + off2 + (k - k1)];
        dst[(size_t)n * ldd + k] = f2bf(v);
    }
}

// FB[e][0:64] = bf16(fbonds[e][0:50]) padded with zeros
__global__ void build_fb(const float* __restrict__ fb, u16* __restrict__ FB, int E)
{
    const int e = blockIdx.x * 4 + (threadIdx.x >> 6);
    if (e >= E) return;
    const int k = threadIdx.x & 63;
    FB[(size_t)e * 64 + k] = (k < 50) ? f2bf(fb[(size_t)e * 50 + k]) : (u16)0;
}

// per-molecule mean over sorted mol_ids; atomh bf16, out fp32
__global__ void segment_mean(const u16* __restrict__ atomh, const int* __restrict__ mol_ids,
                             float* __restrict__ out, int N)
{
    const int m = blockIdx.x;
    const int t = threadIdx.x;
    __shared__ int s_lo, s_hi;
    if (t == 0) {
        int lo = 0, hi = N;
        while (lo < hi) { int mid = (lo + hi) >> 1; if (mol_ids[mid] < m) lo = mid + 1; else hi = mid; }
        s_lo = lo;
        lo = s_lo; hi = N;
        while (lo < hi) { int mid = (lo + hi) >> 1; if (mol_ids[mid] < m + 1) lo = mid + 1; else hi = mid; }
        s_hi = lo;
    }
    __syncthreads();
    const int lo = s_lo, hi = s_hi;
    float sum = 0.f;
    for (int a = lo; a < hi; ++a) sum += bf2f(atomh[(size_t)a * HID + t]);
    const float cnt = (float)((hi - lo) > 1 ? (hi - lo) : 1);
    out[(size_t)m * HID + t] = sum / cnt;
}

extern "C" void kernel_launch(void* const* d_in, const int* in_sizes, int n_in,
                              void* d_out, int out_size, void* d_ws, size_t ws_size,
                              hipStream_t stream)
{
    const float* fatoms = (const float*)d_in[0];
    const float* fbonds = (const float*)d_in[1];
    const int*   agraph = (const int*)d_in[2];
    const int*   bgraph = (const int*)d_in[3];
    const int*   mol_ids = (const int*)d_in[4];
    const float* W_i = (const float*)d_in[7];
    const float* W_h = (const float*)d_in[8];
    const float* W_o = (const float*)d_in[9];
    const float* b_o = (const float*)d_in[10];

    const int N = in_sizes[0] / 39;       // 100000
    const int E = in_sizes[1] / 50;       // 200001
    const int N_MOLS = 1000;
    const int DEPTH = 6;

    const size_t EH = (size_t)E * HID;
    const size_t wbh_sz = (size_t)256 * 320;
    const size_t wbi_sz = (size_t)256 * 64;
    const size_t wbo_sz = (size_t)256 * 320;
    const size_t wsz = wbh_sz + wbi_sz + wbo_sz;
    const size_t fb_sz = (size_t)E * 64;

    const size_t need_nofb = (2 * EH + wsz) * sizeof(u16);
    const size_t need_fb   = (2 * EH + fb_sz + wsz) * sizeof(u16);
    if (ws_size < need_nofb) return;
    const bool use_fb = (ws_size >= need_fb);

    u16* buf0 = (u16*)d_ws;                       // [E][256]
    u16* buf1 = buf0 + EH;                        // [E][256]
    u16* FB   = use_fb ? (buf1 + EH) : nullptr;   // [E][64] bf16 fbonds
    u16* wbh  = (use_fb ? FB + fb_sz : buf1 + EH);
    u16* wbi  = wbh + wbh_sz;
    u16* wbo  = wbi + wbi_sz;

    float* out = (float*)d_out;

    build_wb<<<dim3(256), dim3(64), 0, stream>>>(W_h, 256, 0, 256, W_i, 50, 0, 50, wbh, 320);
    build_wb<<<dim3(256), dim3(64), 0, stream>>>(W_i, 50, 0, 50, W_i, 50, 0, 0, wbi, 64);
    build_wb<<<dim3(256), dim3(64), 0, stream>>>(W_o, 295, 39, 256, W_o, 295, 0, 39, wbo, 320);
    if (use_fb)
        build_fb<<<dim3((E + 3) / 4), dim3(256), 0, stream>>>(fbonds, FB, E);

    const int gE = (E + 63) / 64;     // 3126
    const int gN = (N + 63) / 64;     // 1563

    // layer 0: buf0 = relu(fbonds @ W_i.T)
    if (use_fb)
        fused_layer<<<dim3(gE), dim3(512), 0, stream>>>(
            nullptr, nullptr, 0, FB, 64, 1, nullptr, 0, 0, 0, wbi, 64, nullptr, buf0, E);
    else
        fused_layer<<<dim3(gE), dim3(512), 0, stream>>>(
            nullptr, nullptr, 0, nullptr, 0, 0, fbonds, 50, 50, 1, wbi, 64, nullptr, buf0, E);

    // hidden layers (ping-pong): dst = relu(gather(src)@W_h.T + fbonds@W_i.T)
    u16* src = buf0;
    u16* dst = buf1;
    for (int it = 0; it < DEPTH - 1; ++it) {
        if (use_fb)
            fused_layer<<<dim3(gE), dim3(512), 0, stream>>>(
                src, bgraph, 4, FB, 64, 1, nullptr, 0, 0, 0, wbh, 320, nullptr, dst, E);
        else
            fused_layer<<<dim3(gE), dim3(512), 0, stream>>>(
                src, bgraph, 4, nullptr, 0, 0, fbonds, 50, 50, 1, wbh, 320, nullptr, dst, E);
        u16* tmp = src; src = dst; dst = tmp;
    }
    // after 5 layers: src = buf1 (final message), dst = buf0 (free)

    // output layer: dst = relu(gather_a(src)@W_o[:,39:].T + fatoms@W_o[:,:39].T + b_o)
    fused_layer<<<dim3(gN), dim3(512), 0, stream>>>(
        src, agraph, 4, nullptr, 0, 0, fatoms, 39, 39, 1, wbo, 320, b_o, dst, N);

    // per-molecule mean
    segment_mean<<<dim3(N_MOLS), dim3(256), 0, stream>>>(dst, mol_ids, out, N);
}